// Round 1
// baseline (3911.143 us; speedup 1.0000x reference)
//
#include <hip/hip_runtime.h>
#include <hip/hip_bf16.h>

// ---------------------------------------------------------------------------
// Phase 1a: scatter-add aggregation  agg[dst] += x[src],  deg[dst] += 1
// one thread per (edge, 4-feature group): 1.6M edges * 32 groups
// ---------------------------------------------------------------------------
__global__ __launch_bounds__(256) void sge_scatter(
    const float* __restrict__ x, const int* __restrict__ src,
    const int* __restrict__ dst, float* __restrict__ agg,
    float* __restrict__ deg, int nE) {
  int idx = blockIdx.x * 256 + threadIdx.x;
  int tot = nE * 32;
  if (idx >= tot) return;
  int e = idx >> 5;
  int g = idx & 31;
  int s = src[e];
  int d = dst[e];
  float4 v = *(const float4*)&x[(long long)s * 128 + g * 4];
  float* a = &agg[(long long)d * 128 + g * 4];
  atomicAdd(a + 0, v.x);
  atomicAdd(a + 1, v.y);
  atomicAdd(a + 2, v.z);
  atomicAdd(a + 3, v.w);
  if (g == 0) atomicAdd(&deg[d], 1.0f);
}

// ---------------------------------------------------------------------------
// Phase 1b: z = (agg / max(deg,1)) @ W    [N,128] @ [128,256] -> [N,256]
// block = 256 threads, tile = 32 rows; thread t owns column t for 32 rows
// ---------------------------------------------------------------------------
__global__ __launch_bounds__(256) void sge_gemm(
    const float* __restrict__ agg, const float* __restrict__ deg,
    const float* __restrict__ W, float* __restrict__ z) {
  __shared__ float xs[32][128];
  int n0 = blockIdx.x * 32;
  int t = threadIdx.x;
#pragma unroll
  for (int i = 0; i < 16; ++i) {
    int idx = t + i * 256;      // 0..4095
    int r = idx >> 7;
    int c = idx & 127;
    float dg = deg[n0 + r];
    xs[r][c] = agg[(long long)(n0 + r) * 128 + c] / fmaxf(dg, 1.0f);
  }
  __syncthreads();
  float acc[32];
#pragma unroll
  for (int r = 0; r < 32; ++r) acc[r] = 0.0f;
  for (int k = 0; k < 128; k += 4) {
    float w0 = W[(k + 0) * 256 + t];
    float w1 = W[(k + 1) * 256 + t];
    float w2 = W[(k + 2) * 256 + t];
    float w3 = W[(k + 3) * 256 + t];
#pragma unroll
    for (int r = 0; r < 32; ++r) {
      float4 xv = *(const float4*)&xs[r][k];
      acc[r] = fmaf(xv.x, w0, acc[r]);
      acc[r] = fmaf(xv.y, w1, acc[r]);
      acc[r] = fmaf(xv.z, w2, acc[r]);
      acc[r] = fmaf(xv.w, w3, acc[r]);
    }
  }
#pragma unroll
  for (int r = 0; r < 32; ++r) z[(long long)(n0 + r) * 256 + t] = acc[r];
}

// ---------------------------------------------------------------------------
// Phase 2: debiased Sinkhorn divergence per edge pair + squared-loss reduce.
// One wave (64 lanes) per edge. 32x32 matrices; 2 lanes per row, 16 cols/lane.
// All 4 cost matrices kept in registers (64 VGPR). f/g potentials in LDS.
// ---------------------------------------------------------------------------
__global__ __launch_bounds__(64) void sge_energy(
    const float* __restrict__ z, const int* __restrict__ ep,
    const int* __restrict__ en, float* __restrict__ out, int nP) {
  __shared__ float zx[256], zy[256];
  __shared__ float nx[32], ny[32];
  __shared__ float fab[32], gba[32], faa[32], gbb[32];

  int b = blockIdx.x;
  int l = threadIdx.x;
  bool pos = b < nP;
  int idx = pos ? b : b - nP;
  const int* E = pos ? ep : en;
  int na = E[idx];
  int nb = E[idx + nP];
  const float* zra = z + (long long)na * 256;
  const float* zrb = z + (long long)nb * 256;
#pragma unroll
  for (int t = 0; t < 4; ++t) {
    zx[l + 64 * t] = zra[l + 64 * t];
    zy[l + 64 * t] = zrb[l + 64 * t];
  }
  __syncthreads();
  if (l < 32) {
    float s = 0.0f;
#pragma unroll
    for (int d = 0; d < 8; ++d) { float v = zx[l * 8 + d]; s += v * v; }
    nx[l] = s;
    fab[l] = 0.0f; gba[l] = 0.0f; faa[l] = 0.0f; gbb[l] = 0.0f;
  } else {
    int j = l - 32;
    float s = 0.0f;
#pragma unroll
    for (int d = 0; d < 8; ++d) { float v = zy[j * 8 + d]; s += v * v; }
    ny[j] = s;
  }
  __syncthreads();

  int row = l >> 1;
  int c0 = (l & 1) * 16;

  float xr[8], yr[8];
#pragma unroll
  for (int d = 0; d < 8; ++d) {
    xr[d] = zx[row * 8 + d];
    yr[d] = zy[row * 8 + d];
  }
  float nxr = nx[row];
  float nyr = ny[row];

  float cxy[16], cyx[16], cxx[16], cyy[16];
#pragma unroll
  for (int t = 0; t < 16; ++t) {
    int j = c0 + t;
    float dxy = 0.f, dyx = 0.f, dxx = 0.f, dyy = 0.f;
#pragma unroll
    for (int d = 0; d < 8; ++d) {
      float cx = zx[j * 8 + d];
      float cy = zy[j * 8 + d];
      dxy = fmaf(xr[d], cy, dxy);   // x_row . y_j
      dyx = fmaf(yr[d], cx, dyx);   // y_row . x_j
      dxx = fmaf(xr[d], cx, dxx);
      dyy = fmaf(yr[d], cy, dyy);
    }
    float nxj = nx[j];
    float nyj = ny[j];
    cxy[t] = sqrtf(fmaxf(nxr + nyj - 2.f * dxy, 0.f) + 1e-8f);
    cyx[t] = sqrtf(fmaxf(nyr + nxj - 2.f * dyx, 0.f) + 1e-8f);
    cxx[t] = sqrtf(fmaxf(nxr + nxj - 2.f * dxx, 0.f) + 1e-8f);
    cyy[t] = sqrtf(fmaxf(nyr + nyj - 2.f * dyy, 0.f) + 1e-8f);
  }

  const float LOG32 = 3.46573590279972654709f;
  float epsv = 10.0f;
#pragma unroll 1
  for (int it = 0; it < 9; ++it) {
    float eps = (it == 8) ? 0.05f : epsv;
    float ieps = 1.0f / eps;

    auto softmin = [&](const float (&C)[16], const float* h) -> float {
      float u[16];
#pragma unroll
      for (int t = 0; t < 16; ++t) u[t] = (h[c0 + t] - C[t]) * ieps;
      float m = u[0];
#pragma unroll
      for (int t = 1; t < 16; ++t) m = fmaxf(m, u[t]);
      m = fmaxf(m, __shfl_xor(m, 1));
      float s = 0.0f;
#pragma unroll
      for (int t = 0; t < 16; ++t) s += __expf(u[t] - m);
      s += __shfl_xor(s, 1);
      return -eps * (m + __logf(s) - LOG32);
    };

    float rft = softmin(cxy, gba);   // ft_i  uses g_ba
    float rgt = softmin(cyx, fab);   // gt_j  uses f_ab
    float rfa = softmin(cxx, faa);   // fat_i uses f_aa
    float rgb = softmin(cyy, gbb);   // gbt_j uses g_bb
    __syncthreads();
    if ((l & 1) == 0) {
      fab[row] = 0.5f * (fab[row] + rft);
      gba[row] = 0.5f * (gba[row] + rgt);
      faa[row] = 0.5f * (faa[row] + rfa);
      gbb[row] = 0.5f * (gbb[row] + rgb);
    }
    __syncthreads();
    epsv *= 0.5f;
  }

  float val = (l < 32) ? ((fab[l] - faa[l]) + (gba[l] - gbb[l])) : 0.0f;
#pragma unroll
  for (int k = 1; k < 64; k <<= 1) val += __shfl_xor(val, k);
  if (l == 0) {
    float e = val * (1.0f / 32.0f);
    float term;
    if (pos) {
      term = e * e;
    } else {
      float m = fmaxf(1.0f - e, 0.0f);
      term = m * m;
    }
    atomicAdd(out, term / (float)nP);
  }
}

// ---------------------------------------------------------------------------
extern "C" void kernel_launch(void* const* d_in, const int* in_sizes, int n_in,
                              void* d_out, int out_size, void* d_ws, size_t ws_size,
                              hipStream_t stream) {
  const float* x  = (const float*)d_in[0];
  const int*   ei = (const int*)d_in[1];
  const int*   ep = (const int*)d_in[2];
  const int*   en = (const int*)d_in[3];
  const float* W  = (const float*)d_in[4];
  float* out = (float*)d_out;

  int N  = in_sizes[0] / 128;   // 100000 nodes
  int nE = in_sizes[1] / 2;     // 1600000 edges
  int nP = in_sizes[2] / 2;     // 30000 pos (== neg)

  size_t zBytes   = (size_t)N * 256 * sizeof(float);   // 102.4 MB
  size_t aggBytes = (size_t)N * 128 * sizeof(float);   //  51.2 MB
  size_t degBytes = (size_t)N * sizeof(float);         //   0.4 MB
  if (ws_size < zBytes + aggBytes + degBytes) return;  // ws too small: bail

  char* ws = (char*)d_ws;
  float* z   = (float*)ws;
  float* agg = (float*)(ws + zBytes);
  float* deg = (float*)(ws + zBytes + aggBytes);

  // zero accumulators (agg+deg contiguous) and the output scalar
  hipMemsetAsync(agg, 0, aggBytes + degBytes, stream);
  hipMemsetAsync(out, 0, sizeof(float) * out_size, stream);

  // 1a: scatter aggregation
  {
    int tot = nE * 32;
    int blocks = (tot + 255) / 256;
    sge_scatter<<<blocks, 256, 0, stream>>>(x, ei, ei + nE, agg, deg, nE);
  }
  // 1b: GEMM -> z
  {
    int blocks = (N + 31) / 32;   // N = 100000 = 3125 * 32 exactly
    sge_gemm<<<blocks, 256, 0, stream>>>(agg, deg, W, z);
  }
  // 2: sinkhorn energies + loss reduce
  {
    sge_energy<<<2 * nP, 64, 0, stream>>>(z, ep, en, out, nP);
  }
}

// Round 2
// 1582.271 us; speedup vs baseline: 2.4719x; 2.4719x over previous
//
#include <hip/hip_runtime.h>
#include <hip/hip_bf16.h>

// ---------------------------------------------------------------------------
// Phase 1a (new): CSR build by dst, then gather-aggregate.
//   A: cnt[dst]++                       (int atomics)
//   B1: per-block sums of cnt           -> bsum
//   B2: exclusive scan of bsum (1 wave) -> bsum, offs[N]=nE
//   B3: per-block exclusive scan of cnt -> offs, pos
//   C: sorted_src[atomicAdd(pos[dst])] = src
//   D: agg[n] = (sum_{e in CSR[n]} x[src_e]) / max(deg,1)
// ---------------------------------------------------------------------------

__global__ __launch_bounds__(256) void sge_count(
    const int* __restrict__ dst, int* __restrict__ cnt, int nE) {
  int e = blockIdx.x * 256 + threadIdx.x;
  if (e >= nE) return;
  atomicAdd(&cnt[dst[e]], 1);
}

__global__ __launch_bounds__(256) void sge_blocksum(
    const int* __restrict__ cnt, int* __restrict__ bsum, int N) {
  int i = blockIdx.x * 256 + threadIdx.x;
  int v = (i < N) ? cnt[i] : 0;
#pragma unroll
  for (int o = 1; o < 64; o <<= 1) v += __shfl_xor(v, o);
  __shared__ int ws[4];
  int lane = threadIdx.x & 63, wid = threadIdx.x >> 6;
  if (lane == 0) ws[wid] = v;
  __syncthreads();
  if (threadIdx.x == 0)
    bsum[blockIdx.x] = ws[0] + ws[1] + ws[2] + ws[3];
}

__global__ __launch_bounds__(64) void sge_scan_top(
    int* __restrict__ bsum, int* __restrict__ offs, int nb, int N, int nE) {
  int lane = threadIdx.x;
  int carry = 0;
  for (int base = 0; base < nb; base += 64) {
    int i = base + lane;
    int v = (i < nb) ? bsum[i] : 0;
    int s = v;
#pragma unroll
    for (int o = 1; o < 64; o <<= 1) {
      int t = __shfl_up(s, o);
      if (lane >= o) s += t;
    }
    if (i < nb) bsum[i] = carry + s - v;  // exclusive
    carry += __shfl(s, 63);
  }
  if (lane == 0) offs[N] = nE;
}

__global__ __launch_bounds__(256) void sge_scan_block(
    const int* __restrict__ cnt, const int* __restrict__ bsum,
    int* __restrict__ offs, int* __restrict__ pos, int N) {
  int i = blockIdx.x * 256 + threadIdx.x;
  int v = (i < N) ? cnt[i] : 0;
  int lane = threadIdx.x & 63, wid = threadIdx.x >> 6;
  int s = v;
#pragma unroll
  for (int o = 1; o < 64; o <<= 1) {
    int t = __shfl_up(s, o);
    if (lane >= o) s += t;
  }
  __shared__ int ws[4];
  if (lane == 63) ws[wid] = s;
  __syncthreads();
  int wbase = 0;
  for (int w = 0; w < wid; ++w) wbase += ws[w];
  if (i < N) {
    int o = bsum[blockIdx.x] + wbase + s - v;  // exclusive scan value
    offs[i] = o;
    pos[i] = o;
  }
}

__global__ __launch_bounds__(256) void sge_fill(
    const int* __restrict__ src, const int* __restrict__ dst,
    int* __restrict__ pos, int* __restrict__ sorted_src, int nE) {
  int e = blockIdx.x * 256 + threadIdx.x;
  if (e >= nE) return;
  int p = atomicAdd(&pos[dst[e]], 1);
  sorted_src[p] = src[e];
}

// one 128-thread half-block per node; fuses degree normalization
__global__ __launch_bounds__(256) void sge_gather(
    const float* __restrict__ x, const int* __restrict__ sorted_src,
    const int* __restrict__ offs, float* __restrict__ agg, int N) {
  int node = blockIdx.x * 2 + (threadIdx.x >> 7);
  int c = threadIdx.x & 127;
  if (node >= N) return;
  int e0 = offs[node], e1 = offs[node + 1];
  float acc = 0.0f;
  for (int e = e0; e < e1; ++e) {
    int s = sorted_src[e];  // uniform across the 128 threads -> broadcast
    acc += x[(size_t)s * 128 + c];
  }
  float dg = (float)(e1 - e0);
  agg[(size_t)node * 128 + c] = acc / fmaxf(dg, 1.0f);
}

// ---------------------------------------------------------------------------
// Phase 1b: z = agg @ W    [N,128] @ [128,256] -> [N,256]
// (degree division already fused into gather)
// ---------------------------------------------------------------------------
__global__ __launch_bounds__(256) void sge_gemm(
    const float* __restrict__ agg, const float* __restrict__ W,
    float* __restrict__ z) {
  __shared__ float xs[32][128];
  int n0 = blockIdx.x * 32;
  int t = threadIdx.x;
#pragma unroll
  for (int i = 0; i < 16; ++i) {
    int idx = t + i * 256;  // 0..4095
    int r = idx >> 7;
    int c = idx & 127;
    xs[r][c] = agg[(long long)(n0 + r) * 128 + c];
  }
  __syncthreads();
  float acc[32];
#pragma unroll
  for (int r = 0; r < 32; ++r) acc[r] = 0.0f;
  for (int k = 0; k < 128; k += 4) {
    float w0 = W[(k + 0) * 256 + t];
    float w1 = W[(k + 1) * 256 + t];
    float w2 = W[(k + 2) * 256 + t];
    float w3 = W[(k + 3) * 256 + t];
#pragma unroll
    for (int r = 0; r < 32; ++r) {
      float4 xv = *(const float4*)&xs[r][k];
      acc[r] = fmaf(xv.x, w0, acc[r]);
      acc[r] = fmaf(xv.y, w1, acc[r]);
      acc[r] = fmaf(xv.z, w2, acc[r]);
      acc[r] = fmaf(xv.w, w3, acc[r]);
    }
  }
#pragma unroll
  for (int r = 0; r < 32; ++r) z[(long long)(n0 + r) * 256 + t] = acc[r];
}

// ---------------------------------------------------------------------------
// Phase 2: debiased Sinkhorn divergence per edge pair + squared-loss reduce.
// One wave (64 lanes) per edge. 32x32 matrices; 2 lanes per row, 16 cols/lane.
// ---------------------------------------------------------------------------
__global__ __launch_bounds__(64) void sge_energy(
    const float* __restrict__ z, const int* __restrict__ ep,
    const int* __restrict__ en, float* __restrict__ out, int nP) {
  __shared__ float zx[256], zy[256];
  __shared__ float nx[32], ny[32];
  __shared__ float fab[32], gba[32], faa[32], gbb[32];

  int b = blockIdx.x;
  int l = threadIdx.x;
  bool pos = b < nP;
  int idx = pos ? b : b - nP;
  const int* E = pos ? ep : en;
  int na = E[idx];
  int nb = E[idx + nP];
  const float* zra = z + (long long)na * 256;
  const float* zrb = z + (long long)nb * 256;
#pragma unroll
  for (int t = 0; t < 4; ++t) {
    zx[l + 64 * t] = zra[l + 64 * t];
    zy[l + 64 * t] = zrb[l + 64 * t];
  }
  __syncthreads();
  if (l < 32) {
    float s = 0.0f;
#pragma unroll
    for (int d = 0; d < 8; ++d) { float v = zx[l * 8 + d]; s += v * v; }
    nx[l] = s;
    fab[l] = 0.0f; gba[l] = 0.0f; faa[l] = 0.0f; gbb[l] = 0.0f;
  } else {
    int j = l - 32;
    float s = 0.0f;
#pragma unroll
    for (int d = 0; d < 8; ++d) { float v = zy[j * 8 + d]; s += v * v; }
    ny[j] = s;
  }
  __syncthreads();

  int row = l >> 1;
  int c0 = (l & 1) * 16;

  float xr[8], yr[8];
#pragma unroll
  for (int d = 0; d < 8; ++d) {
    xr[d] = zx[row * 8 + d];
    yr[d] = zy[row * 8 + d];
  }
  float nxr = nx[row];
  float nyr = ny[row];

  float cxy[16], cyx[16], cxx[16], cyy[16];
#pragma unroll
  for (int t = 0; t < 16; ++t) {
    int j = c0 + t;
    float dxy = 0.f, dyx = 0.f, dxx = 0.f, dyy = 0.f;
#pragma unroll
    for (int d = 0; d < 8; ++d) {
      float cx = zx[j * 8 + d];
      float cy = zy[j * 8 + d];
      dxy = fmaf(xr[d], cy, dxy);
      dyx = fmaf(yr[d], cx, dyx);
      dxx = fmaf(xr[d], cx, dxx);
      dyy = fmaf(yr[d], cy, dyy);
    }
    float nxj = nx[j];
    float nyj = ny[j];
    cxy[t] = sqrtf(fmaxf(nxr + nyj - 2.f * dxy, 0.f) + 1e-8f);
    cyx[t] = sqrtf(fmaxf(nyr + nxj - 2.f * dyx, 0.f) + 1e-8f);
    cxx[t] = sqrtf(fmaxf(nxr + nxj - 2.f * dxx, 0.f) + 1e-8f);
    cyy[t] = sqrtf(fmaxf(nyr + nyj - 2.f * dyy, 0.f) + 1e-8f);
  }

  const float LOG32 = 3.46573590279972654709f;
  float epsv = 10.0f;
#pragma unroll 1
  for (int it = 0; it < 9; ++it) {
    float eps = (it == 8) ? 0.05f : epsv;
    float ieps = 1.0f / eps;

    auto softmin = [&](const float (&C)[16], const float* h) -> float {
      float u[16];
#pragma unroll
      for (int t = 0; t < 16; ++t) u[t] = (h[c0 + t] - C[t]) * ieps;
      float m = u[0];
#pragma unroll
      for (int t = 1; t < 16; ++t) m = fmaxf(m, u[t]);
      m = fmaxf(m, __shfl_xor(m, 1));
      float s = 0.0f;
#pragma unroll
      for (int t = 0; t < 16; ++t) s += __expf(u[t] - m);
      s += __shfl_xor(s, 1);
      return -eps * (m + __logf(s) - LOG32);
    };

    float rft = softmin(cxy, gba);
    float rgt = softmin(cyx, fab);
    float rfa = softmin(cxx, faa);
    float rgb = softmin(cyy, gbb);
    __syncthreads();
    if ((l & 1) == 0) {
      fab[row] = 0.5f * (fab[row] + rft);
      gba[row] = 0.5f * (gba[row] + rgt);
      faa[row] = 0.5f * (faa[row] + rfa);
      gbb[row] = 0.5f * (gbb[row] + rgb);
    }
    __syncthreads();
    epsv *= 0.5f;
  }

  float val = (l < 32) ? ((fab[l] - faa[l]) + (gba[l] - gbb[l])) : 0.0f;
#pragma unroll
  for (int k = 1; k < 64; k <<= 1) val += __shfl_xor(val, k);
  if (l == 0) {
    float e = val * (1.0f / 32.0f);
    float term;
    if (pos) {
      term = e * e;
    } else {
      float m = fmaxf(1.0f - e, 0.0f);
      term = m * m;
    }
    atomicAdd(out, term / (float)nP);
  }
}

// ---------------------------------------------------------------------------
extern "C" void kernel_launch(void* const* d_in, const int* in_sizes, int n_in,
                              void* d_out, int out_size, void* d_ws, size_t ws_size,
                              hipStream_t stream) {
  const float* x  = (const float*)d_in[0];
  const int*   ei = (const int*)d_in[1];
  const int*   ep = (const int*)d_in[2];
  const int*   en = (const int*)d_in[3];
  const float* W  = (const float*)d_in[4];
  float* out = (float*)d_out;

  int N  = in_sizes[0] / 128;   // 100000 nodes
  int nE = in_sizes[1] / 2;     // 1600000 edges
  int nP = in_sizes[2] / 2;     // 30000 pos (== neg)

  size_t zBytes   = (size_t)N * 256 * sizeof(float);   // 102.4 MB
  size_t aggBytes = (size_t)N * 128 * sizeof(float);   //  51.2 MB
  if (ws_size < zBytes + aggBytes) return;

  char* ws = (char*)d_ws;
  float* z   = (float*)ws;                 // written LAST (by gemm)
  float* agg = (float*)(ws + zBytes);

  // CSR temporaries overlaid INSIDE the z region (all dead before gemm runs)
  int* cnt        = (int*)ws;              // N
  int* offs       = cnt + N;               // N+1
  int* pos        = offs + N + 1;          // N
  int* bsum       = pos + N;               // nb (<= 4096)
  int* sorted_src = bsum + 4096;           // nE
  // total ints: ~2.0M = 8.1 MB << zBytes

  int nb = (N + 255) / 256;

  hipMemsetAsync(cnt, 0, (size_t)N * sizeof(int), stream);
  hipMemsetAsync(out, 0, sizeof(float) * out_size, stream);

  const int* src = ei;
  const int* dst = ei + nE;

  int eb = (nE + 255) / 256;
  sge_count<<<eb, 256, 0, stream>>>(dst, cnt, nE);
  sge_blocksum<<<nb, 256, 0, stream>>>(cnt, bsum, N);
  sge_scan_top<<<1, 64, 0, stream>>>(bsum, offs, nb, N, nE);
  sge_scan_block<<<nb, 256, 0, stream>>>(cnt, bsum, offs, pos, N);
  sge_fill<<<eb, 256, 0, stream>>>(src, dst, pos, sorted_src, nE);
  sge_gather<<<(N + 1) / 2, 256, 0, stream>>>(x, sorted_src, offs, agg, N);

  sge_gemm<<<(N + 31) / 32, 256, 0, stream>>>(agg, W, z);

  sge_energy<<<2 * nP, 64, 0, stream>>>(z, ep, en, out, nP);
}

// Round 3
// 1427.325 us; speedup vs baseline: 2.7402x; 1.1086x over previous
//
#include <hip/hip_runtime.h>
#include <hip/hip_bf16.h>

// ---------------------------------------------------------------------------
// Phase 1a: CSR build by dst, then gather-aggregate (unchanged from R2)
// ---------------------------------------------------------------------------

__global__ __launch_bounds__(256) void sge_count(
    const int* __restrict__ dst, int* __restrict__ cnt, int nE) {
  int e = blockIdx.x * 256 + threadIdx.x;
  if (e >= nE) return;
  atomicAdd(&cnt[dst[e]], 1);
}

__global__ __launch_bounds__(256) void sge_blocksum(
    const int* __restrict__ cnt, int* __restrict__ bsum, int N) {
  int i = blockIdx.x * 256 + threadIdx.x;
  int v = (i < N) ? cnt[i] : 0;
#pragma unroll
  for (int o = 1; o < 64; o <<= 1) v += __shfl_xor(v, o);
  __shared__ int ws[4];
  int lane = threadIdx.x & 63, wid = threadIdx.x >> 6;
  if (lane == 0) ws[wid] = v;
  __syncthreads();
  if (threadIdx.x == 0)
    bsum[blockIdx.x] = ws[0] + ws[1] + ws[2] + ws[3];
}

__global__ __launch_bounds__(64) void sge_scan_top(
    int* __restrict__ bsum, int* __restrict__ offs, int nb, int N, int nE) {
  int lane = threadIdx.x;
  int carry = 0;
  for (int base = 0; base < nb; base += 64) {
    int i = base + lane;
    int v = (i < nb) ? bsum[i] : 0;
    int s = v;
#pragma unroll
    for (int o = 1; o < 64; o <<= 1) {
      int t = __shfl_up(s, o);
      if (lane >= o) s += t;
    }
    if (i < nb) bsum[i] = carry + s - v;  // exclusive
    carry += __shfl(s, 63);
  }
  if (lane == 0) offs[N] = nE;
}

__global__ __launch_bounds__(256) void sge_scan_block(
    const int* __restrict__ cnt, const int* __restrict__ bsum,
    int* __restrict__ offs, int* __restrict__ pos, int N) {
  int i = blockIdx.x * 256 + threadIdx.x;
  int v = (i < N) ? cnt[i] : 0;
  int lane = threadIdx.x & 63, wid = threadIdx.x >> 6;
  int s = v;
#pragma unroll
  for (int o = 1; o < 64; o <<= 1) {
    int t = __shfl_up(s, o);
    if (lane >= o) s += t;
  }
  __shared__ int ws[4];
  if (lane == 63) ws[wid] = s;
  __syncthreads();
  int wbase = 0;
  for (int w = 0; w < wid; ++w) wbase += ws[w];
  if (i < N) {
    int o = bsum[blockIdx.x] + wbase + s - v;
    offs[i] = o;
    pos[i] = o;
  }
}

__global__ __launch_bounds__(256) void sge_fill(
    const int* __restrict__ src, const int* __restrict__ dst,
    int* __restrict__ pos, int* __restrict__ sorted_src, int nE) {
  int e = blockIdx.x * 256 + threadIdx.x;
  if (e >= nE) return;
  int p = atomicAdd(&pos[dst[e]], 1);
  sorted_src[p] = src[e];
}

__global__ __launch_bounds__(256) void sge_gather(
    const float* __restrict__ x, const int* __restrict__ sorted_src,
    const int* __restrict__ offs, float* __restrict__ agg, int N) {
  int node = blockIdx.x * 2 + (threadIdx.x >> 7);
  int c = threadIdx.x & 127;
  if (node >= N) return;
  int e0 = offs[node], e1 = offs[node + 1];
  float acc = 0.0f;
  for (int e = e0; e < e1; ++e) {
    int s = sorted_src[e];
    acc += x[(size_t)s * 128 + c];
  }
  float dg = (float)(e1 - e0);
  agg[(size_t)node * 128 + c] = acc / fmaxf(dg, 1.0f);
}

// ---------------------------------------------------------------------------
// Phase 1b: z = agg @ W   (unchanged)
// ---------------------------------------------------------------------------
__global__ __launch_bounds__(256) void sge_gemm(
    const float* __restrict__ agg, const float* __restrict__ W,
    float* __restrict__ z) {
  __shared__ float xs[32][128];
  int n0 = blockIdx.x * 32;
  int t = threadIdx.x;
#pragma unroll
  for (int i = 0; i < 16; ++i) {
    int idx = t + i * 256;
    int r = idx >> 7;
    int c = idx & 127;
    xs[r][c] = agg[(long long)(n0 + r) * 128 + c];
  }
  __syncthreads();
  float acc[32];
#pragma unroll
  for (int r = 0; r < 32; ++r) acc[r] = 0.0f;
  for (int k = 0; k < 128; k += 4) {
    float w0 = W[(k + 0) * 256 + t];
    float w1 = W[(k + 1) * 256 + t];
    float w2 = W[(k + 2) * 256 + t];
    float w3 = W[(k + 3) * 256 + t];
#pragma unroll
    for (int r = 0; r < 32; ++r) {
      float4 xv = *(const float4*)&xs[r][k];
      acc[r] = fmaf(xv.x, w0, acc[r]);
      acc[r] = fmaf(xv.y, w1, acc[r]);
      acc[r] = fmaf(xv.z, w2, acc[r]);
      acc[r] = fmaf(xv.w, w3, acc[r]);
    }
  }
#pragma unroll
  for (int r = 0; r < 32; ++r) z[(long long)(n0 + r) * 256 + t] = acc[r];
}

// ---------------------------------------------------------------------------
// Phase 2 (rewritten): one wave per edge pair, one C-row per lane.
//  lanes 0-31  (lane i): row i of C_xy (A) and C_xx (B), potentials fab, faa
//  lanes 32-63 (lane j): row j of C_yx (A) and C_yy (B), potentials gba, gbb
// All C values + u[] in VGPRs; potentials exchanged via per-wave LDS with
// broadcast b128 reads. No __syncthreads (pure intra-wave lockstep).
// ---------------------------------------------------------------------------
__device__ __forceinline__ float dot8(const float xr[8], float4 a0, float4 a1) {
  float d = xr[0] * a0.x;
  d = fmaf(xr[1], a0.y, d);
  d = fmaf(xr[2], a0.z, d);
  d = fmaf(xr[3], a0.w, d);
  d = fmaf(xr[4], a1.x, d);
  d = fmaf(xr[5], a1.y, d);
  d = fmaf(xr[6], a1.z, d);
  d = fmaf(xr[7], a1.w, d);
  return d;
}

__device__ __forceinline__ float softmin32(const float (&C)[32], const float* h,
                                           float k, float eln2, float c32) {
  float u[32];
#pragma unroll
  for (int q = 0; q < 8; ++q) {
    float4 hv = ((const float4*)h)[q];
    u[4 * q + 0] = hv.x - C[4 * q + 0];
    u[4 * q + 1] = hv.y - C[4 * q + 1];
    u[4 * q + 2] = hv.z - C[4 * q + 2];
    u[4 * q + 3] = hv.w - C[4 * q + 3];
  }
  float m16[16];
#pragma unroll
  for (int q = 0; q < 16; ++q) m16[q] = fmaxf(u[q], u[q + 16]);
#pragma unroll
  for (int q = 0; q < 8; ++q) m16[q] = fmaxf(m16[q], m16[q + 8]);
#pragma unroll
  for (int q = 0; q < 4; ++q) m16[q] = fmaxf(m16[q], m16[q + 4]);
  float m = fmaxf(fmaxf(m16[0], m16[1]), fmaxf(m16[2], m16[3]));
  float negmk = -m * k;
  float e[32];
#pragma unroll
  for (int q = 0; q < 32; ++q)
    e[q] = __builtin_amdgcn_exp2f(fmaf(u[q], k, negmk));
#pragma unroll
  for (int q = 0; q < 16; ++q) e[q] += e[q + 16];
#pragma unroll
  for (int q = 0; q < 8; ++q) e[q] += e[q + 8];
#pragma unroll
  for (int q = 0; q < 4; ++q) e[q] += e[q + 4];
  float s = (e[0] + e[1]) + (e[2] + e[3]);
  return c32 - m - eln2 * __builtin_amdgcn_logf(s);
}

__global__ __launch_bounds__(256, 4) void sge_energy(
    const float* __restrict__ z, const int* __restrict__ ep,
    const int* __restrict__ en, float* __restrict__ out, int nP) {
  __shared__ __align__(16) float zbuf[4][512];  // zx[256] | zy[256] per wave
  __shared__ __align__(16) float nrm[4][64];    // nx[32] | ny[32]
  __shared__ __align__(16) float pots[4][128];  // pf | pg | pfa | pgb

  int wid = threadIdx.x >> 6;
  int l = threadIdx.x & 63;
  int pair = blockIdx.x * 4 + wid;
  if (pair >= 2 * nP) return;
  bool isPos = pair < nP;
  int idx = isPos ? pair : pair - nP;
  const int* E = isPos ? ep : en;
  int na = E[idx], nb = E[idx + nP];

  float* zx = zbuf[wid];
  float* zy = zbuf[wid] + 256;
  float* nx = nrm[wid];
  float* ny = nrm[wid] + 32;
  float* pf = pots[wid];        // fab  (written by lo)
  float* pg = pots[wid] + 32;   // gba  (written by hi)
  float* pfa = pots[wid] + 64;  // faa  (written by lo)
  float* pgb = pots[wid] + 96;  // gbb  (written by hi)

  // load z rows, coalesced float4
  {
    const float4* za = (const float4*)(z + (size_t)na * 256);
    const float4* zb = (const float4*)(z + (size_t)nb * 256);
    ((float4*)zx)[l] = za[l];
    ((float4*)zy)[l] = zb[l];
  }
  pots[wid][l] = 0.0f;
  pots[wid][l + 64] = 0.0f;

  int r = l & 31;
  bool lo = l < 32;

  // own row into registers + own squared norm
  const float* zrow = lo ? (zx + r * 8) : (zy + r * 8);
  float xr[8];
  {
    float4 a0 = ((const float4*)zrow)[0];
    float4 a1 = ((const float4*)zrow)[1];
    xr[0] = a0.x; xr[1] = a0.y; xr[2] = a0.z; xr[3] = a0.w;
    xr[4] = a1.x; xr[5] = a1.y; xr[6] = a1.z; xr[7] = a1.w;
  }
  float nself = dot8(xr, ((const float4*)zrow)[0], ((const float4*)zrow)[1]);
  nrm[wid][l] = nself;

  // per-half operand selection (LDS pointers: broadcast reads per half)
  const float* pA = lo ? zy : zx;   // A: C_xy rows (lo) / C_yx rows (hi)
  const float* pB = lo ? zx : zy;   // B: C_xx rows (lo) / C_yy rows (hi)
  const float* pnA = lo ? ny : nx;
  const float* pnB = lo ? nx : ny;
  const float* hA = lo ? pg : pf;   // softmin-A h: gba (lo) / fab (hi)
  const float* hB = lo ? pfa : pgb; // softmin-B h: faa (lo) / gbb (hi)
  float* wA = lo ? pf : pg;         // write: fab (lo) / gba (hi)
  float* wB = lo ? pfa : pgb;       // write: faa (lo) / gbb (hi)

  // build the two C rows (32 regs each)
  float CA[32], CB[32];
#pragma unroll
  for (int j = 0; j < 32; ++j) {
    float4 a0 = ((const float4*)(pA + j * 8))[0];
    float4 a1 = ((const float4*)(pA + j * 8))[1];
    float4 b0 = ((const float4*)(pB + j * 8))[0];
    float4 b1 = ((const float4*)(pB + j * 8))[1];
    float da = dot8(xr, a0, a1);
    float db = dot8(xr, b0, b1);
    float sqa = fmaf(-2.0f, da, nself + pnA[j]);
    float sqb = fmaf(-2.0f, db, nself + pnB[j]);
    CA[j] = __builtin_amdgcn_sqrtf(fmaxf(sqa, 0.0f) + 1e-8f);
    CB[j] = __builtin_amdgcn_sqrtf(fmaxf(sqb, 0.0f) + 1e-8f);
  }

  float PA = 0.0f, PB = 0.0f;  // lo: fab, faa ; hi: gba, gbb
  float epsv = 10.0f;
  const float RLN2 = 1.44269504088896340736f;  // 1/ln2
  const float LN2 = 0.69314718055994530942f;
  const float LN32 = 3.46573590279972654709f;
#pragma unroll 1
  for (int it = 0; it < 9; ++it) {
    float eps = (it == 8) ? 0.05f : epsv;
    float k = RLN2 / eps;
    float eln2 = eps * LN2;
    float c32 = eps * LN32;

    float rA = softmin32(CA, hA, k, eln2, c32);
    float rB = softmin32(CB, hB, k, eln2, c32);
    PA = 0.5f * (PA + rA);
    PB = 0.5f * (PB + rB);
    wA[r] = PA;   // reads of this iter already done (lockstep wave)
    wB[r] = PB;
    epsv *= 0.5f;
  }

  // loss: lo lane i holds fab_i - faa_i ; hi lane j holds gba_j - gbb_j
  float d = PA - PB;
#pragma unroll
  for (int o = 1; o < 64; o <<= 1) d += __shfl_xor(d, o);
  if (l == 0) {
    float e = d * (1.0f / 32.0f);
    float term;
    if (isPos) {
      term = e * e;
    } else {
      float mm = fmaxf(1.0f - e, 0.0f);
      term = mm * mm;
    }
    atomicAdd(out, term / (float)nP);
  }
}

// ---------------------------------------------------------------------------
extern "C" void kernel_launch(void* const* d_in, const int* in_sizes, int n_in,
                              void* d_out, int out_size, void* d_ws, size_t ws_size,
                              hipStream_t stream) {
  const float* x  = (const float*)d_in[0];
  const int*   ei = (const int*)d_in[1];
  const int*   ep = (const int*)d_in[2];
  const int*   en = (const int*)d_in[3];
  const float* W  = (const float*)d_in[4];
  float* out = (float*)d_out;

  int N  = in_sizes[0] / 128;   // 100000 nodes
  int nE = in_sizes[1] / 2;     // 1600000 edges
  int nP = in_sizes[2] / 2;     // 30000 pos (== neg)

  size_t zBytes   = (size_t)N * 256 * sizeof(float);
  size_t aggBytes = (size_t)N * 128 * sizeof(float);
  if (ws_size < zBytes + aggBytes) return;

  char* ws = (char*)d_ws;
  float* z   = (float*)ws;                 // written LAST (by gemm)
  float* agg = (float*)(ws + zBytes);

  // CSR temporaries overlaid inside the z region (dead before gemm)
  int* cnt        = (int*)ws;              // N
  int* offs       = cnt + N;               // N+1
  int* pos        = offs + N + 1;          // N
  int* bsum       = pos + N;               // <= 4096
  int* sorted_src = bsum + 4096;           // nE

  int nb = (N + 255) / 256;

  hipMemsetAsync(cnt, 0, (size_t)N * sizeof(int), stream);
  hipMemsetAsync(out, 0, sizeof(float) * out_size, stream);

  const int* src = ei;
  const int* dst = ei + nE;

  int eb = (nE + 255) / 256;
  sge_count<<<eb, 256, 0, stream>>>(dst, cnt, nE);
  sge_blocksum<<<nb, 256, 0, stream>>>(cnt, bsum, N);
  sge_scan_top<<<1, 64, 0, stream>>>(bsum, offs, nb, N, nE);
  sge_scan_block<<<nb, 256, 0, stream>>>(cnt, bsum, offs, pos, N);
  sge_fill<<<eb, 256, 0, stream>>>(src, dst, pos, sorted_src, nE);
  sge_gather<<<(N + 1) / 2, 256, 0, stream>>>(x, sorted_src, offs, agg, N);

  sge_gemm<<<(N + 31) / 32, 256, 0, stream>>>(agg, W, z);

  sge_energy<<<(2 * nP + 3) / 4, 256, 0, stream>>>(z, ep, en, out, nP);
}

// Round 4
// 1423.272 us; speedup vs baseline: 2.7480x; 1.0028x over previous
//
#include <hip/hip_runtime.h>
#include <hip/hip_bf16.h>

// ---------------------------------------------------------------------------
// Phase 1a: CSR build by dst, then gather-aggregate (unchanged)
// ---------------------------------------------------------------------------

__global__ __launch_bounds__(256) void sge_count(
    const int* __restrict__ dst, int* __restrict__ cnt, int nE) {
  int e = blockIdx.x * 256 + threadIdx.x;
  if (e >= nE) return;
  atomicAdd(&cnt[dst[e]], 1);
}

__global__ __launch_bounds__(256) void sge_blocksum(
    const int* __restrict__ cnt, int* __restrict__ bsum, int N) {
  int i = blockIdx.x * 256 + threadIdx.x;
  int v = (i < N) ? cnt[i] : 0;
#pragma unroll
  for (int o = 1; o < 64; o <<= 1) v += __shfl_xor(v, o);
  __shared__ int ws[4];
  int lane = threadIdx.x & 63, wid = threadIdx.x >> 6;
  if (lane == 0) ws[wid] = v;
  __syncthreads();
  if (threadIdx.x == 0)
    bsum[blockIdx.x] = ws[0] + ws[1] + ws[2] + ws[3];
}

__global__ __launch_bounds__(64) void sge_scan_top(
    int* __restrict__ bsum, int* __restrict__ offs, int nb, int N, int nE) {
  int lane = threadIdx.x;
  int carry = 0;
  for (int base = 0; base < nb; base += 64) {
    int i = base + lane;
    int v = (i < nb) ? bsum[i] : 0;
    int s = v;
#pragma unroll
    for (int o = 1; o < 64; o <<= 1) {
      int t = __shfl_up(s, o);
      if (lane >= o) s += t;
    }
    if (i < nb) bsum[i] = carry + s - v;  // exclusive
    carry += __shfl(s, 63);
  }
  if (lane == 0) offs[N] = nE;
}

__global__ __launch_bounds__(256) void sge_scan_block(
    const int* __restrict__ cnt, const int* __restrict__ bsum,
    int* __restrict__ offs, int* __restrict__ pos, int N) {
  int i = blockIdx.x * 256 + threadIdx.x;
  int v = (i < N) ? cnt[i] : 0;
  int lane = threadIdx.x & 63, wid = threadIdx.x >> 6;
  int s = v;
#pragma unroll
  for (int o = 1; o < 64; o <<= 1) {
    int t = __shfl_up(s, o);
    if (lane >= o) s += t;
  }
  __shared__ int ws[4];
  if (lane == 63) ws[wid] = s;
  __syncthreads();
  int wbase = 0;
  for (int w = 0; w < wid; ++w) wbase += ws[w];
  if (i < N) {
    int o = bsum[blockIdx.x] + wbase + s - v;
    offs[i] = o;
    pos[i] = o;
  }
}

__global__ __launch_bounds__(256) void sge_fill(
    const int* __restrict__ src, const int* __restrict__ dst,
    int* __restrict__ pos, int* __restrict__ sorted_src, int nE) {
  int e = blockIdx.x * 256 + threadIdx.x;
  if (e >= nE) return;
  int p = atomicAdd(&pos[dst[e]], 1);
  sorted_src[p] = src[e];
}

__global__ __launch_bounds__(256) void sge_gather(
    const float* __restrict__ x, const int* __restrict__ sorted_src,
    const int* __restrict__ offs, float* __restrict__ agg, int N) {
  int node = blockIdx.x * 2 + (threadIdx.x >> 7);
  int c = threadIdx.x & 127;
  if (node >= N) return;
  int e0 = offs[node], e1 = offs[node + 1];
  float acc = 0.0f;
  for (int e = e0; e < e1; ++e) {
    int s = sorted_src[e];
    acc += x[(size_t)s * 128 + c];
  }
  float dg = (float)(e1 - e0);
  agg[(size_t)node * 128 + c] = acc / fmaxf(dg, 1.0f);
}

// ---------------------------------------------------------------------------
// Phase 1b: z = agg @ W   (unchanged)
// ---------------------------------------------------------------------------
__global__ __launch_bounds__(256) void sge_gemm(
    const float* __restrict__ agg, const float* __restrict__ W,
    float* __restrict__ z) {
  __shared__ float xs[32][128];
  int n0 = blockIdx.x * 32;
  int t = threadIdx.x;
#pragma unroll
  for (int i = 0; i < 16; ++i) {
    int idx = t + i * 256;
    int r = idx >> 7;
    int c = idx & 127;
    xs[r][c] = agg[(long long)(n0 + r) * 128 + c];
  }
  __syncthreads();
  float acc[32];
#pragma unroll
  for (int r = 0; r < 32; ++r) acc[r] = 0.0f;
  for (int k = 0; k < 128; k += 4) {
    float w0 = W[(k + 0) * 256 + t];
    float w1 = W[(k + 1) * 256 + t];
    float w2 = W[(k + 2) * 256 + t];
    float w3 = W[(k + 3) * 256 + t];
#pragma unroll
    for (int r = 0; r < 32; ++r) {
      float4 xv = *(const float4*)&xs[r][k];
      acc[r] = fmaf(xv.x, w0, acc[r]);
      acc[r] = fmaf(xv.y, w1, acc[r]);
      acc[r] = fmaf(xv.z, w2, acc[r]);
      acc[r] = fmaf(xv.w, w3, acc[r]);
    }
  }
#pragma unroll
  for (int r = 0; r < 32; ++r) z[(long long)(n0 + r) * 256 + t] = acc[r];
}

// ---------------------------------------------------------------------------
// Phase 2 (v3): 2 waves (128 threads) per pair; 2 lanes per matrix row.
//  wave 0: lane (half,row): C_xy row, cols [16*half,16*half+16) -> fab
//          and C_xx same span -> faa
//  wave 1: same for C_yx -> gba and C_yy -> gbb
// Per lane: CA[16], CB[16], u[16] in VGPRs (~64 live, no spill).
// Partner lane = lane^32; combine max/sum via __shfl_xor(.,32).
// Potentials via LDS with 2 barriers/iter.
// ---------------------------------------------------------------------------
__device__ __forceinline__ float dot8(const float xr[8], float4 a0, float4 a1) {
  float d = xr[0] * a0.x;
  d = fmaf(xr[1], a0.y, d);
  d = fmaf(xr[2], a0.z, d);
  d = fmaf(xr[3], a0.w, d);
  d = fmaf(xr[4], a1.x, d);
  d = fmaf(xr[5], a1.y, d);
  d = fmaf(xr[6], a1.z, d);
  d = fmaf(xr[7], a1.w, d);
  return d;
}

__global__ __launch_bounds__(128, 6) void sge_energy(
    const float* __restrict__ z, const int* __restrict__ ep,
    const int* __restrict__ en, float* __restrict__ out, int nP) {
  __shared__ __align__(16) float zbuf[512];   // zx[256] | zy[256]
  __shared__ __align__(16) float nrm[64];     // nx[32] | ny[32]
  __shared__ __align__(16) float pots[128];   // pf | pg | pfa | pgb
  __shared__ float red[2];

  int t = threadIdx.x;
  int w = t >> 6;         // wave: 0 -> (xy,xx), 1 -> (yx,yy)
  int l = t & 63;
  int row = l & 31;
  int half = l >> 5;
  int c0 = half * 16;

  int pair = blockIdx.x;
  bool isPos = pair < nP;
  int idx = isPos ? pair : pair - nP;
  const int* E = isPos ? ep : en;
  int na = E[idx], nb = E[idx + nP];

  // load both z rows (512 floats) with all 128 threads, coalesced float4
  {
    const float4* za = (const float4*)(z + (size_t)na * 256);
    const float4* zb = (const float4*)(z + (size_t)nb * 256);
    ((float4*)zbuf)[t] = (t < 64) ? za[t] : zb[t - 64];
  }
  pots[t] = 0.0f;
  __syncthreads();

  if (t < 64) {
    const float* zr = zbuf + t * 8;  // t<32: x rows, t>=32: y rows
    float s = 0.0f;
#pragma unroll
    for (int d = 0; d < 8; ++d) s += zr[d] * zr[d];
    nrm[t] = s;
  }
  __syncthreads();

  const float* zx = zbuf;
  const float* zy = zbuf + 256;
  float* pf = pots;        // fab
  float* pg = pots + 32;   // gba
  float* pfa = pots + 64;  // faa
  float* pgb = pots + 96;  // gbb

  const float* myrow = (w == 0) ? (zx + row * 8) : (zy + row * 8);
  float xr[8];
  {
    float4 a0 = ((const float4*)myrow)[0];
    float4 a1 = ((const float4*)myrow)[1];
    xr[0] = a0.x; xr[1] = a0.y; xr[2] = a0.z; xr[3] = a0.w;
    xr[4] = a1.x; xr[5] = a1.y; xr[6] = a1.z; xr[7] = a1.w;
  }
  float nself = nrm[(w == 0) ? row : (32 + row)];

  const float* pA = (w == 0) ? zy : zx;          // cols of the cross matrix
  const float* pB = (w == 0) ? zx : zy;          // cols of the self matrix
  const float* pnA = (w == 0) ? (nrm + 32) : nrm;
  const float* pnB = (w == 0) ? nrm : (nrm + 32);
  const float* hA = (w == 0) ? pg : pf;          // h for cross softmin
  const float* hB = (w == 0) ? pfa : pgb;        // h for self softmin
  float* wA = (w == 0) ? pf : pg;
  float* wB = (w == 0) ? pfa : pgb;

  // build the two 16-col row chunks
  float CA[16], CB[16];
#pragma unroll
  for (int jj = 0; jj < 16; ++jj) {
    int j = c0 + jj;
    float4 a0 = ((const float4*)(pA + j * 8))[0];
    float4 a1 = ((const float4*)(pA + j * 8))[1];
    float4 b0 = ((const float4*)(pB + j * 8))[0];
    float4 b1 = ((const float4*)(pB + j * 8))[1];
    float da = dot8(xr, a0, a1);
    float db = dot8(xr, b0, b1);
    float sqa = fmaf(-2.0f, da, nself + pnA[j]);
    float sqb = fmaf(-2.0f, db, nself + pnB[j]);
    CA[jj] = __builtin_amdgcn_sqrtf(fmaxf(sqa, 0.0f) + 1e-8f);
    CB[jj] = __builtin_amdgcn_sqrtf(fmaxf(sqb, 0.0f) + 1e-8f);
  }

  float PA = 0.0f, PB = 0.0f;
  float epsv = 10.0f;
  const float RLN2 = 1.44269504088896340736f;
  const float LN2 = 0.69314718055994530942f;
  const float LN32 = 3.46573590279972654709f;

#pragma unroll 1
  for (int it = 0; it < 9; ++it) {
    float eps = (it == 8) ? 0.05f : epsv;
    float k = RLN2 / eps;
    float eln2 = eps * LN2;
    float c32 = eps * LN32;

    auto softmin16 = [&](const float (&C)[16], const float* h) -> float {
      float u[16];
#pragma unroll
      for (int q = 0; q < 4; ++q) {
        float4 hv = ((const float4*)(h + c0))[q];
        u[4 * q + 0] = hv.x - C[4 * q + 0];
        u[4 * q + 1] = hv.y - C[4 * q + 1];
        u[4 * q + 2] = hv.z - C[4 * q + 2];
        u[4 * q + 3] = hv.w - C[4 * q + 3];
      }
      float m8[8];
#pragma unroll
      for (int q = 0; q < 8; ++q) m8[q] = fmaxf(u[q], u[q + 8]);
#pragma unroll
      for (int q = 0; q < 4; ++q) m8[q] = fmaxf(m8[q], m8[q + 4]);
      float m = fmaxf(fmaxf(m8[0], m8[1]), fmaxf(m8[2], m8[3]));
      m = fmaxf(m, __shfl_xor(m, 32));   // combine with partner half-row
      float negmk = -m * k;
      float e[16];
#pragma unroll
      for (int q = 0; q < 16; ++q)
        e[q] = __builtin_amdgcn_exp2f(fmaf(u[q], k, negmk));
#pragma unroll
      for (int q = 0; q < 8; ++q) e[q] += e[q + 8];
#pragma unroll
      for (int q = 0; q < 4; ++q) e[q] += e[q + 4];
      float s = (e[0] + e[1]) + (e[2] + e[3]);
      s += __shfl_xor(s, 32);
      return c32 - m - eln2 * __builtin_amdgcn_logf(s);
    };

    float rA = softmin16(CA, hA);
    float rB = softmin16(CB, hB);
    PA = 0.5f * (PA + rA);
    PB = 0.5f * (PB + rB);
    __syncthreads();            // all reads of this iter done
    if (half == 0) {
      wA[row] = PA;
      wB[row] = PB;
    }
    __syncthreads();            // writes visible for next iter
    epsv *= 0.5f;
  }

  // pair energy: mean_i(fab-faa) + mean_j(gba-gbb); each row duplicated x2
  float d = PA - PB;
#pragma unroll
  for (int o = 1; o < 64; o <<= 1) d += __shfl_xor(d, o);
  if (l == 0) red[w] = d;
  __syncthreads();
  if (t == 0) {
    float e = (red[0] + red[1]) * (1.0f / 64.0f);
    float term;
    if (isPos) {
      term = e * e;
    } else {
      float mm = fmaxf(1.0f - e, 0.0f);
      term = mm * mm;
    }
    atomicAdd(out, term / (float)nP);
  }
}

// ---------------------------------------------------------------------------
extern "C" void kernel_launch(void* const* d_in, const int* in_sizes, int n_in,
                              void* d_out, int out_size, void* d_ws, size_t ws_size,
                              hipStream_t stream) {
  const float* x  = (const float*)d_in[0];
  const int*   ei = (const int*)d_in[1];
  const int*   ep = (const int*)d_in[2];
  const int*   en = (const int*)d_in[3];
  const float* W  = (const float*)d_in[4];
  float* out = (float*)d_out;

  int N  = in_sizes[0] / 128;   // 100000 nodes
  int nE = in_sizes[1] / 2;     // 1600000 edges
  int nP = in_sizes[2] / 2;     // 30000 pos (== neg)

  size_t zBytes   = (size_t)N * 256 * sizeof(float);
  size_t aggBytes = (size_t)N * 128 * sizeof(float);
  if (ws_size < zBytes + aggBytes) return;

  char* ws = (char*)d_ws;
  float* z   = (float*)ws;                 // written LAST (by gemm)
  float* agg = (float*)(ws + zBytes);

  // CSR temporaries overlaid inside the z region (dead before gemm)
  int* cnt        = (int*)ws;              // N
  int* offs       = cnt + N;               // N+1
  int* pos        = offs + N + 1;          // N
  int* bsum       = pos + N;               // <= 4096
  int* sorted_src = bsum + 4096;           // nE

  int nb = (N + 255) / 256;

  hipMemsetAsync(cnt, 0, (size_t)N * sizeof(int), stream);
  hipMemsetAsync(out, 0, sizeof(float) * out_size, stream);

  const int* src = ei;
  const int* dst = ei + nE;

  int eb = (nE + 255) / 256;
  sge_count<<<eb, 256, 0, stream>>>(dst, cnt, nE);
  sge_blocksum<<<nb, 256, 0, stream>>>(cnt, bsum, N);
  sge_scan_top<<<1, 64, 0, stream>>>(bsum, offs, nb, N, nE);
  sge_scan_block<<<nb, 256, 0, stream>>>(cnt, bsum, offs, pos, N);
  sge_fill<<<eb, 256, 0, stream>>>(src, dst, pos, sorted_src, nE);
  sge_gather<<<(N + 1) / 2, 256, 0, stream>>>(x, sorted_src, offs, agg, N);

  sge_gemm<<<(N + 31) / 32, 256, 0, stream>>>(agg, W, z);

  sge_energy<<<2 * nP, 128, 0, stream>>>(z, ep, en, out, nP);
}

// Round 5
// 1405.557 us; speedup vs baseline: 2.7826x; 1.0126x over previous
//
#include <hip/hip_runtime.h>
#include <hip/hip_bf16.h>

// ---------------------------------------------------------------------------
// Phase 1a: CSR build by dst, then gather-aggregate (unchanged)
// ---------------------------------------------------------------------------

__global__ __launch_bounds__(256) void sge_count(
    const int* __restrict__ dst, int* __restrict__ cnt, int nE) {
  int e = blockIdx.x * 256 + threadIdx.x;
  if (e >= nE) return;
  atomicAdd(&cnt[dst[e]], 1);
}

__global__ __launch_bounds__(256) void sge_blocksum(
    const int* __restrict__ cnt, int* __restrict__ bsum, int N) {
  int i = blockIdx.x * 256 + threadIdx.x;
  int v = (i < N) ? cnt[i] : 0;
#pragma unroll
  for (int o = 1; o < 64; o <<= 1) v += __shfl_xor(v, o);
  __shared__ int ws[4];
  int lane = threadIdx.x & 63, wid = threadIdx.x >> 6;
  if (lane == 0) ws[wid] = v;
  __syncthreads();
  if (threadIdx.x == 0)
    bsum[blockIdx.x] = ws[0] + ws[1] + ws[2] + ws[3];
}

__global__ __launch_bounds__(64) void sge_scan_top(
    int* __restrict__ bsum, int* __restrict__ offs, int nb, int N, int nE) {
  int lane = threadIdx.x;
  int carry = 0;
  for (int base = 0; base < nb; base += 64) {
    int i = base + lane;
    int v = (i < nb) ? bsum[i] : 0;
    int s = v;
#pragma unroll
    for (int o = 1; o < 64; o <<= 1) {
      int t = __shfl_up(s, o);
      if (lane >= o) s += t;
    }
    if (i < nb) bsum[i] = carry + s - v;  // exclusive
    carry += __shfl(s, 63);
  }
  if (lane == 0) offs[N] = nE;
}

__global__ __launch_bounds__(256) void sge_scan_block(
    const int* __restrict__ cnt, const int* __restrict__ bsum,
    int* __restrict__ offs, int* __restrict__ pos, int N) {
  int i = blockIdx.x * 256 + threadIdx.x;
  int v = (i < N) ? cnt[i] : 0;
  int lane = threadIdx.x & 63, wid = threadIdx.x >> 6;
  int s = v;
#pragma unroll
  for (int o = 1; o < 64; o <<= 1) {
    int t = __shfl_up(s, o);
    if (lane >= o) s += t;
  }
  __shared__ int ws[4];
  if (lane == 63) ws[wid] = s;
  __syncthreads();
  int wbase = 0;
  for (int w = 0; w < wid; ++w) wbase += ws[w];
  if (i < N) {
    int o = bsum[blockIdx.x] + wbase + s - v;
    offs[i] = o;
    pos[i] = o;
  }
}

__global__ __launch_bounds__(256) void sge_fill(
    const int* __restrict__ src, const int* __restrict__ dst,
    int* __restrict__ pos, int* __restrict__ sorted_src, int nE) {
  int e = blockIdx.x * 256 + threadIdx.x;
  if (e >= nE) return;
  int p = atomicAdd(&pos[dst[e]], 1);
  sorted_src[p] = src[e];
}

__global__ __launch_bounds__(256) void sge_gather(
    const float* __restrict__ x, const int* __restrict__ sorted_src,
    const int* __restrict__ offs, float* __restrict__ agg, int N) {
  int node = blockIdx.x * 2 + (threadIdx.x >> 7);
  int c = threadIdx.x & 127;
  if (node >= N) return;
  int e0 = offs[node], e1 = offs[node + 1];
  float acc = 0.0f;
  for (int e = e0; e < e1; ++e) {
    int s = sorted_src[e];
    acc += x[(size_t)s * 128 + c];
  }
  float dg = (float)(e1 - e0);
  agg[(size_t)node * 128 + c] = acc / fmaxf(dg, 1.0f);
}

// ---------------------------------------------------------------------------
// Phase 1b: z = agg @ W   (unchanged)
// ---------------------------------------------------------------------------
__global__ __launch_bounds__(256) void sge_gemm(
    const float* __restrict__ agg, const float* __restrict__ W,
    float* __restrict__ z) {
  __shared__ float xs[32][128];
  int n0 = blockIdx.x * 32;
  int t = threadIdx.x;
#pragma unroll
  for (int i = 0; i < 16; ++i) {
    int idx = t + i * 256;
    int r = idx >> 7;
    int c = idx & 127;
    xs[r][c] = agg[(long long)(n0 + r) * 128 + c];
  }
  __syncthreads();
  float acc[32];
#pragma unroll
  for (int r = 0; r < 32; ++r) acc[r] = 0.0f;
  for (int k = 0; k < 128; k += 4) {
    float w0 = W[(k + 0) * 256 + t];
    float w1 = W[(k + 1) * 256 + t];
    float w2 = W[(k + 2) * 256 + t];
    float w3 = W[(k + 3) * 256 + t];
#pragma unroll
    for (int r = 0; r < 32; ++r) {
      float4 xv = *(const float4*)&xs[r][k];
      acc[r] = fmaf(xv.x, w0, acc[r]);
      acc[r] = fmaf(xv.y, w1, acc[r]);
      acc[r] = fmaf(xv.z, w2, acc[r]);
      acc[r] = fmaf(xv.w, w3, acc[r]);
    }
  }
#pragma unroll
  for (int r = 0; r < 32; ++r) z[(long long)(n0 + r) * 256 + t] = acc[r];
}

// ---------------------------------------------------------------------------
// Phase 2 (v5): factorized softmin with squared cost factors.
//   exp((h_j - C_ij)/eps) = E_j * V_ij,  E_j = 2^((h_j - maxh) k2),
//   V_ij = 2^(-C_ij k2);  eps halves each iter  =>  V <- V*V (multiply!).
//   Last iter (eps 0.078125 -> 0.05) recomputes V from retained C.
// Layout: 128 threads = 2 waves per pair; quadrant q = (wave<<1)|(lane>>5):
//   q0: C_xy rows (fab), q1: C_xx (faa), q2: C_yx (gba), q3: C_yy (gbb).
// Lane owns full 32-col row: C[32], V[32] in VGPRs. E exchanged in LDS
// within its own 32-lane group (wave-internal, no block barrier).
// Potentials double-buffered in LDS; ONE __syncthreads per iteration.
// ---------------------------------------------------------------------------
__device__ __forceinline__ float dot8(const float xr[8], float4 a0, float4 a1) {
  float d = xr[0] * a0.x;
  d = fmaf(xr[1], a0.y, d);
  d = fmaf(xr[2], a0.z, d);
  d = fmaf(xr[3], a0.w, d);
  d = fmaf(xr[4], a1.x, d);
  d = fmaf(xr[5], a1.y, d);
  d = fmaf(xr[6], a1.z, d);
  d = fmaf(xr[7], a1.w, d);
  return d;
}

__global__ __launch_bounds__(128, 5) void sge_energy(
    const float* __restrict__ z, const int* __restrict__ ep,
    const int* __restrict__ en, float* __restrict__ out, int nP) {
  __shared__ __align__(16) float zbuf[512];     // zx[256] | zy[256]
  __shared__ __align__(16) float nrm[64];       // nx[32] | ny[32]
  __shared__ __align__(16) float pots[2][128];  // double-buffered potentials
  __shared__ __align__(16) float Ebuf[128];     // per-quadrant E vectors
  __shared__ float red[2];

  int t = threadIdx.x;
  int w = t >> 6;
  int l = t & 63;
  int row = l & 31;
  int q = (w << 1) | (l >> 5);   // 0:xy 1:xx 2:yx 3:yy

  int pair = blockIdx.x;
  bool isPos = pair < nP;
  int idx = isPos ? pair : pair - nP;
  const int* E = isPos ? ep : en;
  int na = E[idx], nb = E[idx + nP];

  // load both z rows (512 floats), coalesced float4
  {
    const float4* za = (const float4*)(z + (size_t)na * 256);
    const float4* zb = (const float4*)(z + (size_t)nb * 256);
    ((float4*)zbuf)[t] = (t < 64) ? za[t] : zb[t - 64];
  }
  pots[0][t] = 0.0f;
  __syncthreads();

  if (t < 64) {
    const float* zr = zbuf + t * 8;
    float s = 0.0f;
#pragma unroll
    for (int d = 0; d < 8; ++d) s += zr[d] * zr[d];
    nrm[t] = s;
  }
  __syncthreads();

  const float* zx = zbuf;
  const float* zy = zbuf + 256;

  // row/col operand selection per quadrant
  const float* zrow = ((q < 2) ? zx : zy) + row * 8;
  bool colx = (q == 1) || (q == 2);
  const float* pcol = colx ? zx : zy;
  const float* pn = colx ? nrm : (nrm + 32);
  float nself = nrm[(q < 2) ? row : (32 + row)];
  int hsel = (q == 0) ? 2 : (q == 1) ? 1 : (q == 2) ? 0 : 3;

  float xr[8];
  {
    float4 a0 = ((const float4*)zrow)[0];
    float4 a1 = ((const float4*)zrow)[1];
    xr[0] = a0.x; xr[1] = a0.y; xr[2] = a0.z; xr[3] = a0.w;
    xr[4] = a1.x; xr[5] = a1.y; xr[6] = a1.z; xr[7] = a1.w;
  }

  const float RLNE = 1.44269504088896340736f;  // 1/ln2
  const float LN2 = 0.69314718055994530942f;
  const float LN32 = 3.46573590279972654709f;
  const float K20 = RLNE / 10.0f;              // k2 at eps=10

  // build C row (keep) and V = 2^(-C*k2_0)
  float C[32], V[32];
#pragma unroll
  for (int j = 0; j < 32; ++j) {
    float4 a0 = ((const float4*)(pcol + j * 8))[0];
    float4 a1 = ((const float4*)(pcol + j * 8))[1];
    float d = dot8(xr, a0, a1);
    float sq = fmaf(-2.0f, d, nself + pn[j]);
    C[j] = __builtin_amdgcn_sqrtf(fmaxf(sq, 0.0f) + 1e-8f);
    V[j] = __builtin_amdgcn_exp2f(-C[j] * K20);
  }

  float P = 0.0f;
  float epsv = 10.0f;
  int pb = 0;
  float* Eq = Ebuf + q * 32;

#pragma unroll 1
  for (int it = 0; it < 9; ++it) {
    float eps = (it == 8) ? 0.05f : epsv;
    float k2 = RLNE / eps;
    float eln2 = eps * LN2;
    float c32 = eps * LN32;

    // V update: squaring for the halving schedule; fresh exp for final eps
    if (it == 8) {
#pragma unroll
      for (int j = 0; j < 32; ++j)
        V[j] = __builtin_amdgcn_exp2f(-C[j] * k2);
    } else if (it > 0) {
#pragma unroll
      for (int j = 0; j < 32; ++j) V[j] *= V[j];
    }

    // column factor E_j: one exp per lane, exchanged within the 32-group
    float h = pots[pb][hsel * 32 + row];
    float m = h;
    m = fmaxf(m, __shfl_xor(m, 1));
    m = fmaxf(m, __shfl_xor(m, 2));
    m = fmaxf(m, __shfl_xor(m, 4));
    m = fmaxf(m, __shfl_xor(m, 8));
    m = fmaxf(m, __shfl_xor(m, 16));
    Eq[row] = __builtin_amdgcn_exp2f((h - m) * k2);
    __builtin_amdgcn_wave_barrier();   // keep write before reads (same wave)

    float s0 = 0.f, s1 = 0.f, s2 = 0.f, s3 = 0.f;
#pragma unroll
    for (int jq = 0; jq < 8; ++jq) {
      float4 Ev = ((const float4*)Eq)[jq];
      s0 = fmaf(Ev.x, V[4 * jq + 0], s0);
      s1 = fmaf(Ev.y, V[4 * jq + 1], s1);
      s2 = fmaf(Ev.z, V[4 * jq + 2], s2);
      s3 = fmaf(Ev.w, V[4 * jq + 3], s3);
    }
    float s = (s0 + s1) + (s2 + s3);

    float res = c32 - m - eln2 * __builtin_amdgcn_logf(s);  // logf = log2
    P = 0.5f * (P + res);
    pots[pb ^ 1][q * 32 + row] = P;
    __syncthreads();
    pb ^= 1;
    epsv *= 0.5f;
  }

  // energy = mean_i(fab - faa) + mean_j(gba - gbb)
  float d = (q & 1) ? -P : P;
#pragma unroll
  for (int o = 1; o < 64; o <<= 1) d += __shfl_xor(d, o);
  if (l == 0) red[w] = d;
  __syncthreads();
  if (t == 0) {
    float e = (red[0] + red[1]) * (1.0f / 32.0f);
    float term;
    if (isPos) {
      term = e * e;
    } else {
      float mm = fmaxf(1.0f - e, 0.0f);
      term = mm * mm;
    }
    atomicAdd(out, term / (float)nP);
  }
}

// ---------------------------------------------------------------------------
extern "C" void kernel_launch(void* const* d_in, const int* in_sizes, int n_in,
                              void* d_out, int out_size, void* d_ws, size_t ws_size,
                              hipStream_t stream) {
  const float* x  = (const float*)d_in[0];
  const int*   ei = (const int*)d_in[1];
  const int*   ep = (const int*)d_in[2];
  const int*   en = (const int*)d_in[3];
  const float* W  = (const float*)d_in[4];
  float* out = (float*)d_out;

  int N  = in_sizes[0] / 128;   // 100000 nodes
  int nE = in_sizes[1] / 2;     // 1600000 edges
  int nP = in_sizes[2] / 2;     // 30000 pos (== neg)

  size_t zBytes   = (size_t)N * 256 * sizeof(float);
  size_t aggBytes = (size_t)N * 128 * sizeof(float);
  if (ws_size < zBytes + aggBytes) return;

  char* ws = (char*)d_ws;
  float* z   = (float*)ws;                 // written LAST (by gemm)
  float* agg = (float*)(ws + zBytes);

  // CSR temporaries overlaid inside the z region (dead before gemm)
  int* cnt        = (int*)ws;              // N
  int* offs       = cnt + N;               // N+1
  int* pos        = offs + N + 1;          // N
  int* bsum       = pos + N;               // <= 4096
  int* sorted_src = bsum + 4096;           // nE

  int nb = (N + 255) / 256;

  hipMemsetAsync(cnt, 0, (size_t)N * sizeof(int), stream);
  hipMemsetAsync(out, 0, sizeof(float) * out_size, stream);

  const int* src = ei;
  const int* dst = ei + nE;

  int eb = (nE + 255) / 256;
  sge_count<<<eb, 256, 0, stream>>>(dst, cnt, nE);
  sge_blocksum<<<nb, 256, 0, stream>>>(cnt, bsum, N);
  sge_scan_top<<<1, 64, 0, stream>>>(bsum, offs, nb, N, nE);
  sge_scan_block<<<nb, 256, 0, stream>>>(cnt, bsum, offs, pos, N);
  sge_fill<<<eb, 256, 0, stream>>>(src, dst, pos, sorted_src, nE);
  sge_gather<<<(N + 1) / 2, 256, 0, stream>>>(x, sorted_src, offs, agg, N);

  sge_gemm<<<(N + 31) / 32, 256, 0, stream>>>(agg, W, z);

  sge_energy<<<2 * nP, 128, 0, stream>>>(z, ep, en, out, nP);
}